// Round 12
// baseline (664.188 us; speedup 1.0000x reference)
//
#include <hip/hip_runtime.h>
#include <hip/hip_cooperative_groups.h>
#include <math.h>

namespace cg = cooperative_groups;

namespace {

constexpr int kH = 500, kW = 500, kNV = 5023, kNF = 9976, kB = 2;
constexpr float kFocal = 1015.0f;
constexpr float kEps = 1e-6f;
constexpr int kNB = 8;                       // z buckets per tile
constexpr int kChunks = 4;                   // face chunks (binning blocks)
constexpr int kFPC = kNF / kChunks;          // 2494 faces per chunk
constexpr int kNBins = kB * 32 * 32 * kNB * kChunks;  // 65536 cells
constexpr unsigned kListCap = 1800000u;      // u16 entries
constexpr int kGrid = 1024, kThr = 256, kTot = kGrid * kThr;

__device__ inline void cross3(float ax, float ay, float az,
                              float bx, float by, float bz,
                              float& cx, float& cy, float& cz) {
  cx = ay * bz - az * by;
  cy = az * bx - ax * bz;
  cz = ax * by - ay * bx;
}

// Edge-separation triangle-vs-tile cull. Bit-identical between count and fill
// phases (same fn, same inputs -> deterministic counts).
__device__ inline bool tileCull(const float4 r0, const float4 r1,
                                float tX0, float tX1, float tY0, float tY1) {
  float hi0 = fmaf(r0.x, r0.x >= 0.f ? tX1 : tX0,
                   fmaf(r0.y, r0.y >= 0.f ? tY1 : tY0, r0.z));
  float lo0 = fmaf(r0.x, r0.x >= 0.f ? tX0 : tX1,
                   fmaf(r0.y, r0.y >= 0.f ? tY0 : tY1, r0.z));
  float hi1 = fmaf(r1.x, r1.x >= 0.f ? tX1 : tX0,
                   fmaf(r1.y, r1.y >= 0.f ? tY1 : tY0, r1.z));
  float lo1 = fmaf(r1.x, r1.x >= 0.f ? tX0 : tX1,
                   fmaf(r1.y, r1.y >= 0.f ? tY0 : tY1, r1.z));
  float m2 = 2.f * r0.w;   // looser than the per-pixel margin -mw: conservative
  return hi0 >= -m2 && hi1 >= -m2 && (1.f - lo0 - lo1) >= -m2;
}

__device__ inline int bucketOf(float zminf, float zlo, float iscale) {
  float t = (zminf - zlo) * iscale;
  t = fminf(fmaxf(t, 0.f), (float)(kNB - 1));
  return (int)t;
}

// Exact reference projection (feeds discrete decisions -> _rn, no FMA).
__device__ inline void projectV(const float* __restrict__ vb, int vi,
                                float& px, float& py, float& zc) {
  float vx = vb[3 * vi], vy = vb[3 * vi + 1], vz = vb[3 * vi + 2];
  float xc = -vx, yc = vy;
  zc = -vz;
  float zs = fmaxf(zc, kEps);
  px = __fsub_rn(0.5f * kW, __fdiv_rn(__fmul_rn(kFocal, xc), zs));
  py = __fsub_rn(0.5f * kH, __fdiv_rn(__fmul_rn(kFocal, yc), zs));
}

// One cooperative kernel, phases separated by grid.sync() (R10 lesson: the 7
// small dependent dispatches cost ~120us -- more than raster itself; fusion
// removes launch+drain boundaries). All phase bodies are verbatim from R10:
// P0 init; P1 normal scatter + P2 face setup (independent -> one phase);
// P3 bin-count (LDS counters, plain stores -- R4 lesson); P4 scan; P5
// bin-fill (identical cull -> identical counts); P6 raster, 2 tiles/block
// (heavy center paired with light corner). 1024 blocks x 256 thr,
// launch_bounds(256,4) -> 4 blocks/CU co-resident guaranteed.
__global__ __launch_bounds__(256, 4) void mega_k(
    const float* __restrict__ verts, const int* __restrict__ faces,
    float* __restrict__ nacc, float4* __restrict__ fdE,
    float4* __restrict__ fdP, unsigned* __restrict__ tb,
    unsigned* __restrict__ zr, unsigned* __restrict__ cnt,
    unsigned short* __restrict__ list, float* __restrict__ out) {
  cg::grid_group grid = cg::this_grid();
  __shared__ float4 sA[256], sB[256], sC[256];   // raster stage (12 KiB)
  __shared__ unsigned lsc[256];                  // bin counters / scan partials
  int bid = blockIdx.x, t = threadIdx.x;
  int gtid = bid * kThr + t;

  // ---------------- P0: zero normal accumulator; init z-range ----------------
  for (int i = gtid; i < kB * kNV * 3; i += kTot) nacc[i] = 0.0f;
  if (gtid < 2 * kB) zr[gtid] = (gtid & 1) ? 0u : 0x7F800000u;
  grid.sync();

  // ---------------- P1: normal scatter accumulation ----------------
  if (gtid < kB * kNF) {
    int b = gtid / kNF, f = gtid - b * kNF;
    int i0 = faces[3 * f + 0], i1 = faces[3 * f + 1], i2 = faces[3 * f + 2];
    const float* vb = verts + (size_t)b * kNV * 3;
    float x0 = vb[3 * i0], y0 = vb[3 * i0 + 1], z0 = vb[3 * i0 + 2];
    float x1 = vb[3 * i1], y1 = vb[3 * i1 + 1], z1 = vb[3 * i1 + 2];
    float x2 = vb[3 * i2], y2 = vb[3 * i2 + 1], z2 = vb[3 * i2 + 2];
    float* nb = nacc + (size_t)b * kNV * 3;
    float cx, cy, cz;
    cross3(x2 - x1, y2 - y1, z2 - z1, x0 - x1, y0 - y1, z0 - z1, cx, cy, cz);
    atomicAdd(nb + 3 * i1 + 0, cx);
    atomicAdd(nb + 3 * i1 + 1, cy);
    atomicAdd(nb + 3 * i1 + 2, cz);
    cross3(x0 - x2, y0 - y2, z0 - z2, x1 - x2, y1 - y2, z1 - z2, cx, cy, cz);
    atomicAdd(nb + 3 * i2 + 0, cx);
    atomicAdd(nb + 3 * i2 + 1, cy);
    atomicAdd(nb + 3 * i2 + 2, cz);
    cross3(x1 - x0, y1 - y0, z1 - z0, x2 - x0, y2 - y0, z2 - z0, cx, cy, cz);
    atomicAdd(nb + 3 * i0 + 0, cx);
    atomicAdd(nb + 3 * i0 + 1, cy);
    atomicAdd(nb + 3 * i0 + 2, cz);
  }

  // ---------------- P2: face setup (independent of P1 outputs) ----------------
  // Outer b loop keeps every wave batch-uniform for the z-range butterfly
  // (R3 lesson: one atomic per wave, not per thread).
  for (int b = 0; b < kB; ++b) {
    int f = gtid;   // kNF < kTot: single pass
    float redMin = INFINITY, redMax = 0.0f;
    if (f < kNF) {
      size_t idx = (size_t)b * kNF + f;
      const float* vb = verts + (size_t)b * kNV * 3;
      int i0 = faces[3 * f + 0], i1 = faces[3 * f + 1], i2 = faces[3 * f + 2];
      float ax, ay, za, bx, by, zb, cx, cy, zc;
      projectV(vb, i0, ax, ay, za);
      projectV(vb, i1, bx, by, zb);
      projectV(vb, i2, cx, cy, zc);
      float A0 = __fsub_rn(by, cy);
      float B0 = __fsub_rn(cx, bx);
      float A1 = __fsub_rn(cy, ay);
      float B1 = __fsub_rn(ax, cx);
      float e = __fsub_rn(ay, cy);
      float den = __fadd_rn(__fmul_rn(A0, B1), __fmul_rn(B0, e));
      bool valid =
          (fabsf(den) >= kEps) && (za > kEps) && (zb > kEps) && (zc > kEps);
      float ds = valid ? den : 1.0f;

      float4* oe = fdE + idx * 3;
      oe[0] = make_float4(cx, cy, A0, B0);
      oe[1] = make_float4(A1, B1, ds, za);
      oe[2] = make_float4(zb, zc, 0.0f, 0.0f);

      float P0 = A0 / ds, Q0 = B0 / ds, R0 = -(A0 * cx + B0 * cy) / ds;
      float P1 = A1 / ds, Q1 = B1 / ds, R1 = -(A1 * cx + B1 * cy) / ds;
      float dza = za - zc, dzb = zb - zc;
      float Zx = dza * P0 + dzb * P1;
      float Zy = dza * Q0 + dzb * Q1;
      float Zc = dza * R0 + dzb * R1 + zc;
      float S0 = (fabsf(P0) + fabsf(Q0)) * 512.f + fabsf(R0);
      float S1 = (fabsf(P1) + fabsf(Q1)) * 512.f + fabsf(R1);
      float Sz = (fabsf(Zx) + fabsf(Zy)) * 512.f + fabsf(Zc);
      float m0 = S0 * 0x1p-18f;
      float m1 = S1 * 0x1p-18f;
      float mw = m0 + m1 + 2e-6f;
      float mz = m0 * fabsf(dza) + m1 * fabsf(dzb) + Sz * 0x1p-18f +
                 0x1p-18f * (fabsf(zc) + fabsf(dza) + fabsf(dzb) + 1.f) + 2e-6f;
      float zminf = fminf(fminf(za, zb), zc);

      float4* op = fdP + idx * 3;
      op[0] = make_float4(P0, Q0, R0, mw);
      op[1] = make_float4(P1, Q1, R1, mz);
      op[2] = make_float4(Zx, Zy, Zc, zminf);

      unsigned pack;
      if (valid) {
        float mnx = fminf(fminf(ax, bx), cx) - 0.5f;
        float mxx = fmaxf(fmaxf(ax, bx), cx) + 0.5f;
        float mny = fminf(fminf(ay, by), cy) - 0.5f;
        float mxy = fmaxf(fmaxf(ay, by), cy) + 0.5f;
        float c0 = fminf(fmaxf(ceilf((mnx - 15.5f) * 0.0625f), 0.f), 31.f);
        float c1 = fminf(fmaxf(floorf((mxx - 0.5f) * 0.0625f), 0.f), 31.f);
        float r0 = fminf(fmaxf(ceilf((mny - 15.5f) * 0.0625f), 0.f), 31.f);
        float r1 = fminf(fmaxf(floorf((mxy - 0.5f) * 0.0625f), 0.f), 31.f);
        unsigned uc0 = (unsigned)c0, uc1 = (unsigned)c1;
        unsigned ur0 = (unsigned)r0, ur1 = (unsigned)r1;
        if (mxx < mnx || mxy < mny) { uc0 = 1; uc1 = 0; }   // degenerate guard
        pack = uc0 | (uc1 << 8) | (ur0 << 16) | (ur1 << 24);
        redMin = zminf;   // zminf > eps > 0 -> uint bit-order == float order
        redMax = zminf;
      } else {
        pack = 1u;   // cxlo=1 > cxhi=0 -> empty
      }
      tb[idx] = pack;
    }
#pragma unroll
    for (int d = 32; d >= 1; d >>= 1) {
      redMin = fminf(redMin, __shfl_xor(redMin, d, 64));
      redMax = fmaxf(redMax, __shfl_xor(redMax, d, 64));
    }
    if ((t & 63) == 0 && redMin < INFINITY) {
      atomicMin(zr + 2 * b + 0, __float_as_uint(redMin));
      atomicMax(zr + 2 * b + 1, __float_as_uint(redMax));
    }
  }
  grid.sync();

  // ---------------- P3: bin COUNT (blocks 0..255 = (c,ty,b)) ----------------
  if (bid < kChunks * 32 * kB) {
    int c = bid & 3, ty = (bid >> 2) & 31, b = bid >> 7;
    size_t bOff = (size_t)b * kNF;
    lsc[t] = 0u;
    __syncthreads();
    float tY0 = 16.f * ty + 0.5f, tY1 = tY0 + 15.f;
    float zlo = __uint_as_float(zr[2 * b]);
    float zhi = __uint_as_float(zr[2 * b + 1]);
    float range = zhi - zlo;
    float iscale = range > 1e-30f ? (float)kNB / range : 0.f;
    int f0 = c * kFPC, f1 = min(kNF, f0 + kFPC);
    for (int f = f0 + t; f < f1; f += kThr) {
      unsigned pk = tb[bOff + f];
      int cx0 = pk & 0xFF, cx1 = (pk >> 8) & 0xFF;
      int ry0 = (pk >> 16) & 0xFF, ry1 = (pk >> 24) & 0xFF;
      if (ty < ry0 || ty > ry1 || cx0 > cx1) continue;
      const float4* rp = fdP + (bOff + f) * 3;
      float4 r0 = rp[0], r1 = rp[1], r2 = rp[2];
      int q = bucketOf(r2.w, zlo, iscale);
      for (int tx = cx0; tx <= cx1; ++tx) {
        float tX0 = 16.f * tx + 0.5f, tX1 = tX0 + 15.f;
        if (tileCull(r0, r1, tX0, tX1, tY0, tY1))
          atomicAdd(&lsc[tx * kNB + q], 1u);
      }
    }
    __syncthreads();
    unsigned gcell =
        (((unsigned)(b * 32 + ty) * 32) * kNB + (unsigned)t) * kChunks +
        (unsigned)c;
    cnt[gcell] = lsc[t];
  }
  grid.sync();

  // ---------------- P4: exclusive scan (block 0) ----------------
  if (bid == 0) {
    constexpr int PER = kNBins / kThr;   // 256
    unsigned s = 0;
    for (int i = 0; i < PER; ++i) s += cnt[t * PER + i];
    lsc[t] = s;
    __syncthreads();
    for (int d = 1; d < kThr; d <<= 1) {
      unsigned v = (t >= d) ? lsc[t - d] : 0u;
      __syncthreads();
      lsc[t] += v;
      __syncthreads();
    }
    unsigned r = lsc[t] - s;   // exclusive prefix of this thread's chunk
    for (int i = 0; i < PER; ++i) {
      unsigned v = cnt[t * PER + i];
      cnt[t * PER + i] = r;
      r += v;
    }
    if (t == kThr - 1) cnt[kNBins] = r;
  }
  grid.sync();

  // ---------------- P5: bin FILL (identical cull -> identical counts) -------
  if (bid < kChunks * 32 * kB) {
    int c = bid & 3, ty = (bid >> 2) & 31, b = bid >> 7;
    size_t bOff = (size_t)b * kNF;
    unsigned gcell =
        (((unsigned)(b * 32 + ty) * 32) * kNB + (unsigned)t) * kChunks +
        (unsigned)c;
    lsc[t] = cnt[gcell];
    __syncthreads();
    float tY0 = 16.f * ty + 0.5f, tY1 = tY0 + 15.f;
    float zlo = __uint_as_float(zr[2 * b]);
    float zhi = __uint_as_float(zr[2 * b + 1]);
    float range = zhi - zlo;
    float iscale = range > 1e-30f ? (float)kNB / range : 0.f;
    int f0 = c * kFPC, f1 = min(kNF, f0 + kFPC);
    for (int f = f0 + t; f < f1; f += kThr) {
      unsigned pk = tb[bOff + f];
      int cx0 = pk & 0xFF, cx1 = (pk >> 8) & 0xFF;
      int ry0 = (pk >> 16) & 0xFF, ry1 = (pk >> 24) & 0xFF;
      if (ty < ry0 || ty > ry1 || cx0 > cx1) continue;
      const float4* rp = fdP + (bOff + f) * 3;
      float4 r0 = rp[0], r1 = rp[1], r2 = rp[2];
      int q = bucketOf(r2.w, zlo, iscale);
      for (int tx = cx0; tx <= cx1; ++tx) {
        float tX0 = 16.f * tx + 0.5f, tX1 = tX0 + 15.f;
        if (tileCull(r0, r1, tX0, tX1, tY0, tY1)) {
          unsigned pos = atomicAdd(&lsc[tx * kNB + q], 1u);
          if (pos < kListCap) list[pos] = (unsigned short)f;
        }
      }
    }
  }
  grid.sync();

  // ---------------- P6: raster, 2 tiles per block ----------------
  // Pairing (b=0: ty,tx) with (b=1: ty+16,tx+16 mod 32): heavy central tile
  // pairs with a light corner tile -> balanced tail.
  for (int pass = 0; pass < 2; ++pass) {
    int b, tyb, txb;
    if (pass == 0) {
      b = 0; tyb = bid >> 5; txb = bid & 31;
    } else {
      b = 1; tyb = ((bid >> 5) + 16) & 31; txb = ((bid & 31) + 16) & 31;
    }
    size_t bOff = (size_t)b * kNF;
    int tx = t & 15, ty = t >> 4;
    int x = txb * 16 + tx;
    int y = tyb * 16 + ty;
    float xp = (float)x + 0.5f;
    float yp = (float)y + 0.5f;
    bool live = (x < kW && y < kH);
    float zmin = live ? INFINITY : -INFINITY;   // dead px never block the break
    int best = 0x7FFFFFFF;
    float bw0 = 0.f, bw1 = 0.f, bw2 = 0.f;

    float zlo = __uint_as_float(zr[2 * b]);
    float zhi = __uint_as_float(zr[2 * b + 1]);
    float range = zhi - zlo;
    float bwid = range > 1e-30f ? range * (1.f / kNB) : 0.f;
    const unsigned* offT =
        cnt + (unsigned)((b * 32 + tyb) * 32 + txb) * kNB * kChunks;

    for (int q = 0; q < kNB; ++q) {
      if (q > 0) {
        float lb = zlo + (float)q * bwid * (1.f - 1e-5f) - 2e-5f;
        if (__syncthreads_and(zmin < lb)) break;
      }
      unsigned s = offT[q * kChunks], e = offT[(q + 1) * kChunks];
      for (unsigned base = s; base < e; base += kThr) {
        int n = min(256u, e - base);
        __syncthreads();
        if (t < n) {
          unsigned fi = list[base + t];
          const float4* rp = fdP + (bOff + fi) * 3;
          float4 r0 = rp[0], r1 = rp[1], r2 = rp[2];
          r2.w = __int_as_float((int)fi);
          sA[t] = r0;
          sB[t] = r1;
          sC[t] = r2;
        }
        __syncthreads();
        for (int k = 0; k < n; ++k) {
          float4 a = sA[k], bq = sB[k], c = sC[k];
          float w0a = fmaf(a.x, xp, fmaf(a.y, yp, a.z));
          float w1a = fmaf(bq.x, xp, fmaf(bq.y, yp, bq.z));
          float w2a = 1.f - w0a - w1a;
          float zl = fmaf(c.x, xp, fmaf(c.y, yp, c.z));
          float wmin = fminf(fminf(w0a, w1a), w2a);
          if (wmin >= -a.w && zl <= zmin + bq.w) {
            // Exact path: replicate reference fp32 rounding bit-for-bit.
            int fi = __float_as_int(c.w);
            const float4* ep = fdE + (bOff + fi) * 3;
            float4 e0 = ep[0], e1 = ep[1], e2 = ep[2];
            float dx = __fsub_rn(xp, e0.x), dy = __fsub_rn(yp, e0.y);
            float num0 = __fadd_rn(__fmul_rn(e0.z, dx), __fmul_rn(e0.w, dy));
            float num1 = __fadd_rn(__fmul_rn(e1.x, dx), __fmul_rn(e1.y, dy));
            float w0 = __fdiv_rn(num0, e1.z);
            float w1 = __fdiv_rn(num1, e1.z);
            float w2 = __fsub_rn(__fsub_rn(1.f, w0), w1);
            if (w0 >= 0.f && w1 >= 0.f && w2 >= 0.f) {
              float z = __fadd_rn(
                  __fadd_rn(__fmul_rn(w0, e1.w), __fmul_rn(w1, e2.x)),
                  __fmul_rn(w2, e2.y));
              if (z < zmin || (z == zmin && fi < best)) {
                zmin = z; best = fi; bw0 = w0; bw1 = w1; bw2 = w2;
              }
            }
          }
        }
      }
    }

    if (live) {
      float rv, av;
      if (zmin < INFINITY) {
        int i0 = faces[3 * best + 0], i1 = faces[3 * best + 1],
            i2 = faces[3 * best + 2];
        const float* vb = verts + (size_t)b * kNV * 3;
        const float* nb = nacc + (size_t)b * kNV * 3;
        float n0x = nb[3 * i0], n0y = nb[3 * i0 + 1], n0z = nb[3 * i0 + 2];
        float n1x = nb[3 * i1], n1y = nb[3 * i1 + 1], n1z = nb[3 * i1 + 2];
        float n2x = nb[3 * i2], n2y = nb[3 * i2 + 1], n2z = nb[3 * i2 + 2];
        float d0 = fmaxf(sqrtf(n0x * n0x + n0y * n0y + n0z * n0z), kEps);
        float d1 = fmaxf(sqrtf(n1x * n1x + n1y * n1y + n1z * n1z), kEps);
        float d2 = fmaxf(sqrtf(n2x * n2x + n2y * n2y + n2z * n2z), kEps);
        n0x /= d0; n0y /= d0; n0z /= d0;
        n1x /= d1; n1y /= d1; n1z /= d1;
        n2x /= d2; n2y /= d2; n2z /= d2;
        float px_ = bw0 * vb[3 * i0 + 0] + bw1 * vb[3 * i1 + 0] + bw2 * vb[3 * i2 + 0];
        float py_ = bw0 * vb[3 * i0 + 1] + bw1 * vb[3 * i1 + 1] + bw2 * vb[3 * i2 + 1];
        float pz_ = bw0 * vb[3 * i0 + 2] + bw1 * vb[3 * i1 + 2] + bw2 * vb[3 * i2 + 2];
        float nx = bw0 * n0x + bw1 * n1x + bw2 * n2x;
        float ny = bw0 * n0y + bw1 * n1y + bw2 * n2y;
        float nz = bw0 * n0z + bw1 * n1z + bw2 * n2z;
        float nn = sqrtf(nx * nx + ny * ny + nz * nz);
        float nd = fmaxf(nn, kEps);
        nx /= nd; ny /= nd; nz /= nd;
        float pn = sqrtf(px_ * px_ + py_ * py_ + pz_ * pz_);
        float pd = fmaxf(pn, kEps);
        float lx = -px_ / pd, ly = -py_ / pd, lz = -pz_ / pd;
        float sdot = nx * lx + ny * ly + nz * lz;
        float ndl = fmaxf(sdot, 0.0f);
        float rx = 2.0f * sdot * nx - lx;
        float ry = 2.0f * sdot * ny - ly;
        float rz = 2.0f * sdot * nz - lz;
        float vdr = fmaxf(lx * rx + ly * ry + lz * rz, 0.0f);
        float qv = vdr;   // vdr^64 via 6 squarings
        qv = qv * qv; qv = qv * qv; qv = qv * qv;
        qv = qv * qv; qv = qv * qv; qv = qv * qv;
        float shade = 0.5f * (0.5f + 0.3f * ndl) + 0.2f * qv;
        rv = fminf(fmaxf(shade, 0.0f), 255.0f);
        av = 1.0f;
      } else {
        rv = 1.0f;
        av = 0.0f;
      }
      ((float4*)out)[((size_t)b * kH + y) * kW + x] = make_float4(rv, rv, rv, av);
    }
  }
}

}  // namespace

extern "C" void kernel_launch(void* const* d_in, const int* in_sizes, int n_in,
                              void* d_out, int out_size, void* d_ws, size_t ws_size,
                              hipStream_t stream) {
  (void)in_sizes; (void)n_in; (void)out_size; (void)ws_size;
  const float* verts = (const float*)d_in[0];   // (B, NV, 3) f32
  const int* faces = (const int*)d_in[1];       // (NF, 3) i32
  float* out = (float*)d_out;                   // (B, H, W, 4) f32
  float* ws = (float*)d_ws;

  // ws layout (float offsets; total ~6.1 MB <= proven ws >= 6.523 MB):
  //   nacc @ 0          (30,138)
  //   fdE  @ 71,680     (float4 x 59,856)
  //   fdP  @ 311,296    (float4 x 59,856)
  //   tb   @ 550,912    (u32 x 19,952)
  //   zr   @ 570,880    (u32 x 4)
  //   cnt  @ 571,008    (u32 x 65,537)  [doubles as scanned offsets]
  //   list @ 702,208    (u16 x 1,800,000)
  float* nacc = ws;
  float4* fdE = (float4*)(ws + 71680);
  float4* fdP = (float4*)(ws + 311296);
  unsigned* tb = (unsigned*)(ws + 550912);
  unsigned* zr = (unsigned*)(ws + 570880);
  unsigned* cnt = (unsigned*)(ws + 571008);
  unsigned short* list = (unsigned short*)(ws + 702208);

  void* args[] = {&verts, &faces, &nacc, &fdE, &fdP,
                  &tb,    &zr,    &cnt,  &list, &out};
  hipLaunchCooperativeKernel((const void*)mega_k, dim3(kGrid), dim3(kThr),
                             args, 0, stream);
}

// Round 13
// 205.898 us; speedup vs baseline: 3.2258x; 3.2258x over previous
//
#include <hip/hip_runtime.h>
#include <math.h>

namespace {

constexpr int kH = 500, kW = 500, kNV = 5023, kNF = 9976, kB = 2;
constexpr float kFocal = 1015.0f;
constexpr float kEps = 1e-6f;
constexpr int kNB = 8;                       // z buckets per tile
constexpr int kChunks = 4;                   // face chunks (binning blocks)
constexpr int kFPC = kNF / kChunks;          // 2494 faces per chunk
constexpr int kNBins = kB * 32 * 32 * kNB * kChunks;  // 65536 cells
constexpr unsigned kListCap = 1800000u;      // u16 entries

// ---------------------------------------------------------------- utilities
__device__ inline void cross3(float ax, float ay, float az,
                              float bx, float by, float bz,
                              float& cx, float& cy, float& cz) {
  cx = ay * bz - az * by;
  cy = az * bx - ax * bz;
  cz = ax * by - ay * bx;
}

// Edge-separation triangle-vs-tile cull. Bit-identical between count and fill
// passes (same fn, same inputs -> deterministic counts).
__device__ inline bool tileCull(const float4 r0, const float4 r1,
                                float tX0, float tX1, float tY0, float tY1) {
  float hi0 = fmaf(r0.x, r0.x >= 0.f ? tX1 : tX0,
                   fmaf(r0.y, r0.y >= 0.f ? tY1 : tY0, r0.z));
  float lo0 = fmaf(r0.x, r0.x >= 0.f ? tX0 : tX1,
                   fmaf(r0.y, r0.y >= 0.f ? tY0 : tY1, r0.z));
  float hi1 = fmaf(r1.x, r1.x >= 0.f ? tX1 : tX0,
                   fmaf(r1.y, r1.y >= 0.f ? tY1 : tY0, r1.z));
  float lo1 = fmaf(r1.x, r1.x >= 0.f ? tX0 : tX1,
                   fmaf(r1.y, r1.y >= 0.f ? tY0 : tY1, r1.z));
  float m2 = 2.f * r0.w;   // looser than the per-pixel margin -mw: conservative
  return hi0 >= -m2 && hi1 >= -m2 && (1.f - lo0 - lo1) >= -m2;
}

__device__ inline int bucketOf(float zminf, float zlo, float iscale) {
  float t = (zminf - zlo) * iscale;
  t = fminf(fmaxf(t, 0.f), (float)(kNB - 1));
  return (int)t;
}

// Exact reference projection (feeds discrete decisions -> _rn, no FMA).
__device__ inline void projectV(const float* __restrict__ vb, int vi,
                                float& px, float& py, float& zc) {
  float vx = vb[3 * vi], vy = vb[3 * vi + 1], vz = vb[3 * vi + 2];
  float xc = -vx, yc = vy;
  zc = -vz;
  float zs = fmaxf(zc, kEps);
  px = __fsub_rn(0.5f * kW, __fdiv_rn(__fmul_rn(kFocal, xc), zs));
  py = __fsub_rn(0.5f * kH, __fdiv_rn(__fmul_rn(kFocal, yc), zs));
}

// ---------------------------------------------------------------- kernels
// FUSED: per-(b,f) normal scatter-accumulation (independent of setup outputs;
// nacc pre-zeroed by hipMemsetAsync) + face setup. Same 9 vertex floats feed
// both (R12 lesson: fuse via ordinary kernels, NOT cooperative grid.sync --
// grid.sync cost 664us total). zr split: zrMin=zr[0..1] (memset 0xFF;
// atomicMin-safe, valid z bits < 0x7F800000), zrMax=zr[2..3] (memset 0).
// fdE (3 float4): {cx,cy,A0,B0} {A1,B1,den,za} {zb,zc,0,0}   (exact path)
// fdP (3 float4): {P0,Q0,R0,mw} {P1,Q1,R1,mz} {Zx,Zy,Zc,zminf} (prefilter)
// tb  (1 u32): packed tile ranges {cxlo,cxhi,rylo,ryhi} u8 each.
__global__ void setup_k(const float* __restrict__ verts,
                        const int* __restrict__ faces,
                        float* __restrict__ nacc,
                        float4* __restrict__ fdE,
                        float4* __restrict__ fdP,
                        unsigned* __restrict__ tb,
                        unsigned* __restrict__ zr) {
  int f = blockIdx.x * 256 + threadIdx.x;
  int b = blockIdx.y;
  bool act = (f < kNF);
  float redMin = INFINITY, redMax = 0.0f;   // neutral for inactive/invalid
  if (act) {
    size_t idx = (size_t)b * kNF + f;
    const float* vb = verts + (size_t)b * kNV * 3;
    int i0 = faces[3 * f + 0], i1 = faces[3 * f + 1], i2 = faces[3 * f + 2];
    // ---- normal scatter (raw world-space verts) ----
    {
      float x0 = vb[3 * i0], y0 = vb[3 * i0 + 1], z0 = vb[3 * i0 + 2];
      float x1 = vb[3 * i1], y1 = vb[3 * i1 + 1], z1 = vb[3 * i1 + 2];
      float x2 = vb[3 * i2], y2 = vb[3 * i2 + 1], z2 = vb[3 * i2 + 2];
      float* nb = nacc + (size_t)b * kNV * 3;
      float cx, cy, cz;
      cross3(x2 - x1, y2 - y1, z2 - z1, x0 - x1, y0 - y1, z0 - z1, cx, cy, cz);
      atomicAdd(nb + 3 * i1 + 0, cx);
      atomicAdd(nb + 3 * i1 + 1, cy);
      atomicAdd(nb + 3 * i1 + 2, cz);
      cross3(x0 - x2, y0 - y2, z0 - z2, x1 - x2, y1 - y2, z1 - z2, cx, cy, cz);
      atomicAdd(nb + 3 * i2 + 0, cx);
      atomicAdd(nb + 3 * i2 + 1, cy);
      atomicAdd(nb + 3 * i2 + 2, cz);
      cross3(x1 - x0, y1 - y0, z1 - z0, x2 - x0, y2 - y0, z2 - z0, cx, cy, cz);
      atomicAdd(nb + 3 * i0 + 0, cx);
      atomicAdd(nb + 3 * i0 + 1, cy);
      atomicAdd(nb + 3 * i0 + 2, cz);
    }
    // ---- face setup (exact _rn projection inline) ----
    float ax, ay, za, bx, by, zb, cx, cy, zc;
    projectV(vb, i0, ax, ay, za);
    projectV(vb, i1, bx, by, zb);
    projectV(vb, i2, cx, cy, zc);
    float A0 = __fsub_rn(by, cy);
    float B0 = __fsub_rn(cx, bx);
    float A1 = __fsub_rn(cy, ay);
    float B1 = __fsub_rn(ax, cx);
    float e = __fsub_rn(ay, cy);
    float den = __fadd_rn(__fmul_rn(A0, B1), __fmul_rn(B0, e));
    bool valid =
        (fabsf(den) >= kEps) && (za > kEps) && (zb > kEps) && (zc > kEps);
    float ds = valid ? den : 1.0f;

    float4* oe = fdE + idx * 3;
    oe[0] = make_float4(cx, cy, A0, B0);
    oe[1] = make_float4(A1, B1, ds, za);
    oe[2] = make_float4(zb, zc, 0.0f, 0.0f);

    float P0 = A0 / ds, Q0 = B0 / ds, R0 = -(A0 * cx + B0 * cy) / ds;
    float P1 = A1 / ds, Q1 = B1 / ds, R1 = -(A1 * cx + B1 * cy) / ds;
    float dza = za - zc, dzb = zb - zc;
    float Zx = dza * P0 + dzb * P1;
    float Zy = dza * Q0 + dzb * Q1;
    float Zc = dza * R0 + dzb * R1 + zc;
    float S0 = (fabsf(P0) + fabsf(Q0)) * 512.f + fabsf(R0);
    float S1 = (fabsf(P1) + fabsf(Q1)) * 512.f + fabsf(R1);
    float Sz = (fabsf(Zx) + fabsf(Zy)) * 512.f + fabsf(Zc);
    float m0 = S0 * 0x1p-18f;
    float m1 = S1 * 0x1p-18f;
    float mw = m0 + m1 + 2e-6f;
    float mz = m0 * fabsf(dza) + m1 * fabsf(dzb) + Sz * 0x1p-18f +
               0x1p-18f * (fabsf(zc) + fabsf(dza) + fabsf(dzb) + 1.f) + 2e-6f;
    float zminf = fminf(fminf(za, zb), zc);

    float4* op = fdP + idx * 3;
    op[0] = make_float4(P0, Q0, R0, mw);
    op[1] = make_float4(P1, Q1, R1, mz);
    op[2] = make_float4(Zx, Zy, Zc, zminf);

    unsigned pack;
    if (valid) {
      float mnx = fminf(fminf(ax, bx), cx) - 0.5f;
      float mxx = fmaxf(fmaxf(ax, bx), cx) + 0.5f;
      float mny = fminf(fminf(ay, by), cy) - 0.5f;
      float mxy = fmaxf(fmaxf(ay, by), cy) + 0.5f;
      float c0 = fminf(fmaxf(ceilf((mnx - 15.5f) * 0.0625f), 0.f), 31.f);
      float c1 = fminf(fmaxf(floorf((mxx - 0.5f) * 0.0625f), 0.f), 31.f);
      float r0 = fminf(fmaxf(ceilf((mny - 15.5f) * 0.0625f), 0.f), 31.f);
      float r1 = fminf(fmaxf(floorf((mxy - 0.5f) * 0.0625f), 0.f), 31.f);
      unsigned uc0 = (unsigned)c0, uc1 = (unsigned)c1;
      unsigned ur0 = (unsigned)r0, ur1 = (unsigned)r1;
      if (mxx < mnx || mxy < mny) { uc0 = 1; uc1 = 0; }   // degenerate guard
      pack = uc0 | (uc1 << 8) | (ur0 << 16) | (ur1 << 24);
      redMin = zminf;   // zminf > eps > 0 -> uint bit-order == float order
      redMax = zminf;
    } else {
      pack = 1u;   // cxlo=1 > cxhi=0 -> empty
    }
    tb[idx] = pack;
  }
  // Wave-level z-range butterfly -> one atomic per wave (R3 lesson).
#pragma unroll
  for (int d = 32; d >= 1; d >>= 1) {
    redMin = fminf(redMin, __shfl_xor(redMin, d, 64));
    redMax = fmaxf(redMax, __shfl_xor(redMax, d, 64));
  }
  if ((threadIdx.x & 63) == 0 && redMin < INFINITY) {
    atomicMin(zr + b, __float_as_uint(redMin));        // zrMin
    atomicMax(zr + 2 + b, __float_as_uint(redMax));    // zrMax
  }
}

// Block-local LDS binning (no global atomics -- R4 lesson). COUNT: LDS
// atomics then plain-store per-(cell,chunk) counts. FILL: seed cursors from
// scanned offsets; identical cull -> identical counts -> no overflow.
template <bool FILL>
__global__ __launch_bounds__(256) void bin_k(
    const float4* __restrict__ fdP, const unsigned* __restrict__ tb,
    const unsigned* __restrict__ zr, unsigned* __restrict__ cnt,
    unsigned short* __restrict__ list) {
  __shared__ unsigned lc[256];
  int c = blockIdx.x, ty = blockIdx.y, b = blockIdx.z;
  size_t bOff = (size_t)b * kNF;
  int t = threadIdx.x;
  unsigned gcell = (((unsigned)(b * 32 + ty) * 32) * kNB + (unsigned)t) *
                       kChunks + (unsigned)c;
  lc[t] = FILL ? cnt[gcell] : 0u;
  __syncthreads();

  float tY0 = 16.f * ty + 0.5f, tY1 = tY0 + 15.f;
  float zlo = __uint_as_float(zr[b]);
  float zhi = __uint_as_float(zr[2 + b]);
  float range = zhi - zlo;
  float iscale = range > 1e-30f ? (float)kNB / range : 0.f;
  int f0 = c * kFPC, f1 = min(kNF, f0 + kFPC);
  for (int f = f0 + t; f < f1; f += 256) {
    unsigned pk = tb[bOff + f];
    int cx0 = pk & 0xFF, cx1 = (pk >> 8) & 0xFF;
    int ry0 = (pk >> 16) & 0xFF, ry1 = (pk >> 24) & 0xFF;
    if (ty < ry0 || ty > ry1 || cx0 > cx1) continue;
    const float4* rp = fdP + (bOff + f) * 3;
    float4 r0 = rp[0], r1 = rp[1], r2 = rp[2];
    int q = bucketOf(r2.w, zlo, iscale);
    for (int tx = cx0; tx <= cx1; ++tx) {
      float tX0 = 16.f * tx + 0.5f, tX1 = tX0 + 15.f;
      if (tileCull(r0, r1, tX0, tX1, tY0, tY1)) {
        if (FILL) {
          unsigned pos = atomicAdd(&lc[tx * kNB + q], 1u);
          if (pos < kListCap) list[pos] = (unsigned short)f;
        } else {
          atomicAdd(&lc[tx * kNB + q], 1u);
        }
      }
    }
  }
  __syncthreads();
  if (!FILL) cnt[gcell] = lc[t];
}

// In-place exclusive scan over 65,536 cells; sentinel at cnt[kNBins].
__global__ __launch_bounds__(1024) void scan_k(unsigned* __restrict__ cnt) {
  constexpr int PER = kNBins / 1024;   // 64
  __shared__ unsigned part[1024];
  int t = threadIdx.x;
  unsigned s = 0;
  for (int i = 0; i < PER; ++i) s += cnt[t * PER + i];
  part[t] = s;
  __syncthreads();
  for (int d = 1; d < 1024; d <<= 1) {
    unsigned v = (t >= d) ? part[t - d] : 0u;
    __syncthreads();
    part[t] += v;
    __syncthreads();
  }
  unsigned r = part[t] - s;   // exclusive prefix of this thread's chunk
  for (int i = 0; i < PER; ++i) {
    unsigned v = cnt[t * PER + i];
    cnt[t * PER + i] = r;
    r += v;
  }
  if (t == 1023) cnt[kNBins] = r;   // total
}

// 16x16-pixel tile per 256-thread block -- measured-best R5/R10 structure
// (80us; vs 86 4-plane / 107 flat / 128 dbuf / 200 unstaged / 664 coop).
// Per z-bucket (front-to-back): conservative early-break via
// __syncthreads_and; per 256-candidate chunk: barrier, LDS stage, barrier,
// compute. Discrete decisions replicate reference fp32 rounding; (z,idx)
// lex-min == jnp.argmin first-min. Shading fused; normals normalized here.
__global__ __launch_bounds__(256) void raster_k(
    const float4* __restrict__ fdP, const float4* __restrict__ fdE,
    const unsigned* __restrict__ off, const unsigned short* __restrict__ list,
    const unsigned* __restrict__ zr, const float* __restrict__ verts,
    const float* __restrict__ nacc, const int* __restrict__ faces,
    float* __restrict__ out) {
  __shared__ float4 sA[256], sB[256], sC[256];   // 12 KiB stage
  int b = blockIdx.z;
  size_t bOff = (size_t)b * kNF;
  int t = threadIdx.x;
  int tx = t & 15, ty = t >> 4;
  int x = blockIdx.x * 16 + tx;
  int y = blockIdx.y * 16 + ty;
  float xp = (float)x + 0.5f;
  float yp = (float)y + 0.5f;
  bool live = (x < kW && y < kH);
  float zmin = live ? INFINITY : -INFINITY;   // dead px never block the break
  int best = 0x7FFFFFFF;
  float bw0 = 0.f, bw1 = 0.f, bw2 = 0.f;

  float zlo = __uint_as_float(zr[b]);
  float zhi = __uint_as_float(zr[2 + b]);
  float range = zhi - zlo;
  float bwid = range > 1e-30f ? range * (1.f / kNB) : 0.f;
  const unsigned* offT =
      off + (unsigned)((b * 32 + blockIdx.y) * 32 + blockIdx.x) * kNB * kChunks;

  for (int q = 0; q < kNB; ++q) {
    if (q > 0) {
      float lb = zlo + (float)q * bwid * (1.f - 1e-5f) - 2e-5f;
      if (__syncthreads_and(zmin < lb)) break;
    }
    unsigned s = offT[q * kChunks], e = offT[(q + 1) * kChunks];
    for (unsigned base = s; base < e; base += 256) {
      int n = min(256u, e - base);
      __syncthreads();
      if (t < n) {
        unsigned fi = list[base + t];
        const float4* rp = fdP + (bOff + fi) * 3;
        float4 r0 = rp[0], r1 = rp[1], r2 = rp[2];
        r2.w = __int_as_float((int)fi);
        sA[t] = r0;
        sB[t] = r1;
        sC[t] = r2;
      }
      __syncthreads();
      for (int k = 0; k < n; ++k) {
        float4 a = sA[k], bq = sB[k], c = sC[k];
        float w0a = fmaf(a.x, xp, fmaf(a.y, yp, a.z));
        float w1a = fmaf(bq.x, xp, fmaf(bq.y, yp, bq.z));
        float w2a = 1.f - w0a - w1a;
        float zl = fmaf(c.x, xp, fmaf(c.y, yp, c.z));
        float wmin = fminf(fminf(w0a, w1a), w2a);
        if (wmin >= -a.w && zl <= zmin + bq.w) {
          // Exact path: replicate reference fp32 rounding bit-for-bit.
          int fi = __float_as_int(c.w);
          const float4* ep = fdE + (bOff + fi) * 3;
          float4 e0 = ep[0], e1 = ep[1], e2 = ep[2];
          float dx = __fsub_rn(xp, e0.x), dy = __fsub_rn(yp, e0.y);
          float num0 = __fadd_rn(__fmul_rn(e0.z, dx), __fmul_rn(e0.w, dy));
          float num1 = __fadd_rn(__fmul_rn(e1.x, dx), __fmul_rn(e1.y, dy));
          float w0 = __fdiv_rn(num0, e1.z);
          float w1 = __fdiv_rn(num1, e1.z);
          float w2 = __fsub_rn(__fsub_rn(1.f, w0), w1);
          if (w0 >= 0.f && w1 >= 0.f && w2 >= 0.f) {
            float z = __fadd_rn(
                __fadd_rn(__fmul_rn(w0, e1.w), __fmul_rn(w1, e2.x)),
                __fmul_rn(w2, e2.y));
            if (z < zmin || (z == zmin && fi < best)) {
              zmin = z; best = fi; bw0 = w0; bw1 = w1; bw2 = w2;
            }
          }
        }
      }
    }
  }

  if (!live) return;

  float rv, av;
  if (zmin < INFINITY) {
    int i0 = faces[3 * best + 0], i1 = faces[3 * best + 1], i2 = faces[3 * best + 2];
    const float* vb = verts + (size_t)b * kNV * 3;
    const float* nb = nacc + (size_t)b * kNV * 3;
    // Normalize each vertex normal (continuous path).
    float n0x = nb[3 * i0], n0y = nb[3 * i0 + 1], n0z = nb[3 * i0 + 2];
    float n1x = nb[3 * i1], n1y = nb[3 * i1 + 1], n1z = nb[3 * i1 + 2];
    float n2x = nb[3 * i2], n2y = nb[3 * i2 + 1], n2z = nb[3 * i2 + 2];
    float d0 = fmaxf(sqrtf(n0x * n0x + n0y * n0y + n0z * n0z), kEps);
    float d1 = fmaxf(sqrtf(n1x * n1x + n1y * n1y + n1z * n1z), kEps);
    float d2 = fmaxf(sqrtf(n2x * n2x + n2y * n2y + n2z * n2z), kEps);
    n0x /= d0; n0y /= d0; n0z /= d0;
    n1x /= d1; n1y /= d1; n1z /= d1;
    n2x /= d2; n2y /= d2; n2z /= d2;
    float px_ = bw0 * vb[3 * i0 + 0] + bw1 * vb[3 * i1 + 0] + bw2 * vb[3 * i2 + 0];
    float py_ = bw0 * vb[3 * i0 + 1] + bw1 * vb[3 * i1 + 1] + bw2 * vb[3 * i2 + 1];
    float pz_ = bw0 * vb[3 * i0 + 2] + bw1 * vb[3 * i1 + 2] + bw2 * vb[3 * i2 + 2];
    float nx = bw0 * n0x + bw1 * n1x + bw2 * n2x;
    float ny = bw0 * n0y + bw1 * n1y + bw2 * n2y;
    float nz = bw0 * n0z + bw1 * n1z + bw2 * n2z;
    float nn = sqrtf(nx * nx + ny * ny + nz * nz);
    float nd = fmaxf(nn, kEps);
    nx /= nd; ny /= nd; nz /= nd;
    float pn = sqrtf(px_ * px_ + py_ * py_ + pz_ * pz_);
    float pd = fmaxf(pn, kEps);
    float lx = -px_ / pd, ly = -py_ / pd, lz = -pz_ / pd;
    float sdot = nx * lx + ny * ly + nz * lz;
    float ndl = fmaxf(sdot, 0.0f);
    float rx = 2.0f * sdot * nx - lx;
    float ry = 2.0f * sdot * ny - ly;
    float rz = 2.0f * sdot * nz - lz;
    float vdr = fmaxf(lx * rx + ly * ry + lz * rz, 0.0f);
    float qv = vdr;   // vdr^64 via 6 squarings
    qv = qv * qv; qv = qv * qv; qv = qv * qv;
    qv = qv * qv; qv = qv * qv; qv = qv * qv;
    float shade = 0.5f * (0.5f + 0.3f * ndl) + 0.2f * qv;
    rv = fminf(fmaxf(shade, 0.0f), 255.0f);
    av = 1.0f;
  } else {
    rv = 1.0f;
    av = 0.0f;
  }
  ((float4*)out)[((size_t)b * kH + y) * kW + x] = make_float4(rv, rv, rv, av);
}

}  // namespace

extern "C" void kernel_launch(void* const* d_in, const int* in_sizes, int n_in,
                              void* d_out, int out_size, void* d_ws, size_t ws_size,
                              hipStream_t stream) {
  (void)in_sizes; (void)n_in; (void)out_size; (void)ws_size;
  const float* verts = (const float*)d_in[0];   // (B, NV, 3) f32
  const int* faces = (const int*)d_in[1];       // (NF, 3) i32
  float* out = (float*)d_out;                   // (B, H, W, 4) f32
  float* ws = (float*)d_ws;

  // ws layout (float offsets; total ~6.1 MB <= proven ws >= 6.523 MB):
  //   nacc @ 0          (30,138)
  //   fdE  @ 71,680     (float4 x 59,856)
  //   fdP  @ 311,296    (float4 x 59,856)
  //   tb   @ 550,912    (u32 x 19,952)
  //   zr   @ 570,880    (u32 x 4: [0..1]=min (0xFF init), [2..3]=max (0 init))
  //   cnt  @ 571,008    (u32 x 65,537)  [doubles as scanned offsets]
  //   list @ 702,208    (u16 x 1,800,000)
  float* nacc = ws;
  float4* fdE = (float4*)(ws + 71680);
  float4* fdP = (float4*)(ws + 311296);
  unsigned* tb = (unsigned*)(ws + 550912);
  unsigned* zr = (unsigned*)(ws + 570880);
  unsigned* cnt = (unsigned*)(ws + 571008);
  unsigned short* list = (unsigned short*)(ws + 702208);

  // Init via memsets (cheaper than a kernel dispatch; graph-capture legal).
  hipMemsetAsync(nacc, 0, (size_t)kB * kNV * 3 * sizeof(float), stream);
  hipMemsetAsync(zr, 0xFF, 2 * sizeof(unsigned), stream);       // zrMin
  hipMemsetAsync(zr + 2, 0x00, 2 * sizeof(unsigned), stream);   // zrMax

  hipLaunchKernelGGL(setup_k, dim3((kNF + 255) / 256, kB), dim3(256), 0,
                     stream, verts, faces, nacc, fdE, fdP, tb, zr);
  hipLaunchKernelGGL((bin_k<false>), dim3(kChunks, 32, kB), dim3(256), 0,
                     stream, fdP, tb, zr, cnt, list);
  hipLaunchKernelGGL(scan_k, dim3(1), dim3(1024), 0, stream, cnt);
  hipLaunchKernelGGL((bin_k<true>), dim3(kChunks, 32, kB), dim3(256), 0,
                     stream, fdP, tb, zr, cnt, list);
  hipLaunchKernelGGL(raster_k, dim3(32, 32, kB), dim3(256), 0, stream,
                     fdP, fdE, cnt, list, zr, verts, nacc, faces, out);
}

// Round 14
// 151.522 us; speedup vs baseline: 4.3834x; 1.3589x over previous
//
#include <hip/hip_runtime.h>
#include <math.h>

namespace {

constexpr int kH = 500, kW = 500, kNV = 5023, kNF = 9976, kB = 2;
constexpr float kFocal = 1015.0f;
constexpr float kEps = 1e-6f;
constexpr int kNB = 8;                       // z buckets per tile
constexpr int kChunks = 8;                   // face chunks (binning blocks)
constexpr int kFPC = kNF / kChunks;          // 1247 faces per chunk
constexpr unsigned kListCap = 1800000u;      // u16 entries (same bound as R12)

// ---------------------------------------------------------------- utilities
__device__ inline void cross3(float ax, float ay, float az,
                              float bx, float by, float bz,
                              float& cx, float& cy, float& cz) {
  cx = ay * bz - az * by;
  cy = az * bx - ax * bz;
  cz = ax * by - ay * bx;
}

// Edge-separation triangle-vs-tile cull. Bit-identical between count and fill
// passes (same fn, same inputs -> deterministic counts).
__device__ inline bool tileCull(const float4 r0, const float4 r1,
                                float tX0, float tX1, float tY0, float tY1) {
  float hi0 = fmaf(r0.x, r0.x >= 0.f ? tX1 : tX0,
                   fmaf(r0.y, r0.y >= 0.f ? tY1 : tY0, r0.z));
  float lo0 = fmaf(r0.x, r0.x >= 0.f ? tX0 : tX1,
                   fmaf(r0.y, r0.y >= 0.f ? tY0 : tY1, r0.z));
  float hi1 = fmaf(r1.x, r1.x >= 0.f ? tX1 : tX0,
                   fmaf(r1.y, r1.y >= 0.f ? tY1 : tY0, r1.z));
  float lo1 = fmaf(r1.x, r1.x >= 0.f ? tX0 : tX1,
                   fmaf(r1.y, r1.y >= 0.f ? tY0 : tY1, r1.z));
  float m2 = 2.f * r0.w;   // looser than the per-pixel margin -mw: conservative
  return hi0 >= -m2 && hi1 >= -m2 && (1.f - lo0 - lo1) >= -m2;
}

__device__ inline int bucketOf(float zminf, float zlo, float iscale) {
  float t = (zminf - zlo) * iscale;
  t = fminf(fmaxf(t, 0.f), (float)(kNB - 1));
  return (int)t;
}

// Exact reference projection (feeds discrete decisions -> _rn, no FMA).
__device__ inline void projectV(const float* __restrict__ vb, int vi,
                                float& px, float& py, float& zc) {
  float vx = vb[3 * vi], vy = vb[3 * vi + 1], vz = vb[3 * vi + 2];
  float xc = -vx, yc = vy;
  zc = -vz;
  float zs = fmaxf(zc, kEps);
  px = __fsub_rn(0.5f * kW, __fdiv_rn(__fmul_rn(kFocal, xc), zs));
  py = __fsub_rn(0.5f * kH, __fdiv_rn(__fmul_rn(kFocal, yc), zs));
}

// ---------------------------------------------------------------- kernels
// FUSED per-(b,f): normal scatter-accumulation (nacc pre-zeroed by memset)
// + face setup with inline exact _rn projection. zr: [0..1]=min (0xFF init),
// [2..3]=max (0 init), [4]=list cursor (0 init).
__global__ void setup_k(const float* __restrict__ verts,
                        const int* __restrict__ faces,
                        float* __restrict__ nacc,
                        float4* __restrict__ fdE,
                        float4* __restrict__ fdP,
                        unsigned* __restrict__ tb,
                        unsigned* __restrict__ zr) {
  int f = blockIdx.x * 256 + threadIdx.x;
  int b = blockIdx.y;
  bool act = (f < kNF);
  float redMin = INFINITY, redMax = 0.0f;   // neutral for inactive/invalid
  if (act) {
    size_t idx = (size_t)b * kNF + f;
    const float* vb = verts + (size_t)b * kNV * 3;
    int i0 = faces[3 * f + 0], i1 = faces[3 * f + 1], i2 = faces[3 * f + 2];
    // ---- normal scatter (raw world-space verts) ----
    {
      float x0 = vb[3 * i0], y0 = vb[3 * i0 + 1], z0 = vb[3 * i0 + 2];
      float x1 = vb[3 * i1], y1 = vb[3 * i1 + 1], z1 = vb[3 * i1 + 2];
      float x2 = vb[3 * i2], y2 = vb[3 * i2 + 1], z2 = vb[3 * i2 + 2];
      float* nb = nacc + (size_t)b * kNV * 3;
      float cx, cy, cz;
      cross3(x2 - x1, y2 - y1, z2 - z1, x0 - x1, y0 - y1, z0 - z1, cx, cy, cz);
      atomicAdd(nb + 3 * i1 + 0, cx);
      atomicAdd(nb + 3 * i1 + 1, cy);
      atomicAdd(nb + 3 * i1 + 2, cz);
      cross3(x0 - x2, y0 - y2, z0 - z2, x1 - x2, y1 - y2, z1 - z2, cx, cy, cz);
      atomicAdd(nb + 3 * i2 + 0, cx);
      atomicAdd(nb + 3 * i2 + 1, cy);
      atomicAdd(nb + 3 * i2 + 2, cz);
      cross3(x1 - x0, y1 - y0, z1 - z0, x2 - x0, y2 - y0, z2 - z0, cx, cy, cz);
      atomicAdd(nb + 3 * i0 + 0, cx);
      atomicAdd(nb + 3 * i0 + 1, cy);
      atomicAdd(nb + 3 * i0 + 2, cz);
    }
    // ---- face setup ----
    float ax, ay, za, bx, by, zb, cx, cy, zc;
    projectV(vb, i0, ax, ay, za);
    projectV(vb, i1, bx, by, zb);
    projectV(vb, i2, cx, cy, zc);
    float A0 = __fsub_rn(by, cy);
    float B0 = __fsub_rn(cx, bx);
    float A1 = __fsub_rn(cy, ay);
    float B1 = __fsub_rn(ax, cx);
    float e = __fsub_rn(ay, cy);
    float den = __fadd_rn(__fmul_rn(A0, B1), __fmul_rn(B0, e));
    bool valid =
        (fabsf(den) >= kEps) && (za > kEps) && (zb > kEps) && (zc > kEps);
    float ds = valid ? den : 1.0f;

    float4* oe = fdE + idx * 3;
    oe[0] = make_float4(cx, cy, A0, B0);
    oe[1] = make_float4(A1, B1, ds, za);
    oe[2] = make_float4(zb, zc, 0.0f, 0.0f);

    float P0 = A0 / ds, Q0 = B0 / ds, R0 = -(A0 * cx + B0 * cy) / ds;
    float P1 = A1 / ds, Q1 = B1 / ds, R1 = -(A1 * cx + B1 * cy) / ds;
    float dza = za - zc, dzb = zb - zc;
    float Zx = dza * P0 + dzb * P1;
    float Zy = dza * Q0 + dzb * Q1;
    float Zc = dza * R0 + dzb * R1 + zc;
    float S0 = (fabsf(P0) + fabsf(Q0)) * 512.f + fabsf(R0);
    float S1 = (fabsf(P1) + fabsf(Q1)) * 512.f + fabsf(R1);
    float Sz = (fabsf(Zx) + fabsf(Zy)) * 512.f + fabsf(Zc);
    float m0 = S0 * 0x1p-18f;
    float m1 = S1 * 0x1p-18f;
    float mw = m0 + m1 + 2e-6f;
    float mz = m0 * fabsf(dza) + m1 * fabsf(dzb) + Sz * 0x1p-18f +
               0x1p-18f * (fabsf(zc) + fabsf(dza) + fabsf(dzb) + 1.f) + 2e-6f;
    float zminf = fminf(fminf(za, zb), zc);

    float4* op = fdP + idx * 3;
    op[0] = make_float4(P0, Q0, R0, mw);
    op[1] = make_float4(P1, Q1, R1, mz);
    op[2] = make_float4(Zx, Zy, Zc, zminf);

    unsigned pack;
    if (valid) {
      float mnx = fminf(fminf(ax, bx), cx) - 0.5f;
      float mxx = fmaxf(fmaxf(ax, bx), cx) + 0.5f;
      float mny = fminf(fminf(ay, by), cy) - 0.5f;
      float mxy = fmaxf(fmaxf(ay, by), cy) + 0.5f;
      float c0 = fminf(fmaxf(ceilf((mnx - 15.5f) * 0.0625f), 0.f), 31.f);
      float c1 = fminf(fmaxf(floorf((mxx - 0.5f) * 0.0625f), 0.f), 31.f);
      float r0 = fminf(fmaxf(ceilf((mny - 15.5f) * 0.0625f), 0.f), 31.f);
      float r1 = fminf(fmaxf(floorf((mxy - 0.5f) * 0.0625f), 0.f), 31.f);
      unsigned uc0 = (unsigned)c0, uc1 = (unsigned)c1;
      unsigned ur0 = (unsigned)r0, ur1 = (unsigned)r1;
      if (mxx < mnx || mxy < mny) { uc0 = 1; uc1 = 0; }   // degenerate guard
      pack = uc0 | (uc1 << 8) | (ur0 << 16) | (ur1 << 24);
      redMin = zminf;   // zminf > eps > 0 -> uint bit-order == float order
      redMax = zminf;
    } else {
      pack = 1u;   // cxlo=1 > cxhi=0 -> empty
    }
    tb[idx] = pack;
  }
  // Wave-level z-range butterfly -> one atomic per wave (R3 lesson).
#pragma unroll
  for (int d = 32; d >= 1; d >>= 1) {
    redMin = fminf(redMin, __shfl_xor(redMin, d, 64));
    redMax = fmaxf(redMax, __shfl_xor(redMax, d, 64));
  }
  if ((threadIdx.x & 63) == 0 && redMin < INFINITY) {
    atomicMin(zr + b, __float_as_uint(redMin));        // zrMin
    atomicMax(zr + 2 + b, __float_as_uint(redMax));    // zrMax
  }
}

// SINGLE-DISPATCH binning (replaces count + global-scan + fill, R12->R13):
// per (c,ty,b) block: LDS count -> intra-block LDS scan -> ONE global
// atomicAdd claims a contiguous list segment (512 atomics total; R4 lesson:
// few atomics fine) -> write absolute per-cell offsets to cnt[block][257]
// -> identical-cull fill pass (faces L2-hot). Segment ORDER is racy but
// per-cell candidate SETS are deterministic; raster's (z,idx) lex-min is
// order-independent -> deterministic output.
__global__ __launch_bounds__(256) void bin_k(
    const float4* __restrict__ fdP, const unsigned* __restrict__ tb,
    unsigned* __restrict__ zr, unsigned* __restrict__ cnt,
    unsigned short* __restrict__ list) {
  __shared__ unsigned lc[256];
  __shared__ unsigned segBase;
  int c = blockIdx.x, ty = blockIdx.y, b = blockIdx.z;
  size_t bOff = (size_t)b * kNF;
  int t = threadIdx.x;
  lc[t] = 0u;
  __syncthreads();

  float tY0 = 16.f * ty + 0.5f, tY1 = tY0 + 15.f;
  float zlo = __uint_as_float(zr[b]);
  float zhi = __uint_as_float(zr[2 + b]);
  float range = zhi - zlo;
  float iscale = range > 1e-30f ? (float)kNB / range : 0.f;
  int f0 = c * kFPC, f1 = min(kNF, f0 + kFPC);

  // ---- pass 1: count into LDS ----
  for (int f = f0 + t; f < f1; f += 256) {
    unsigned pk = tb[bOff + f];
    int cx0 = pk & 0xFF, cx1 = (pk >> 8) & 0xFF;
    int ry0 = (pk >> 16) & 0xFF, ry1 = (pk >> 24) & 0xFF;
    if (ty < ry0 || ty > ry1 || cx0 > cx1) continue;
    const float4* rp = fdP + (bOff + f) * 3;
    float4 r0 = rp[0], r1 = rp[1], r2 = rp[2];
    int q = bucketOf(r2.w, zlo, iscale);
    for (int tx = cx0; tx <= cx1; ++tx) {
      float tX0 = 16.f * tx + 0.5f, tX1 = tX0 + 15.f;
      if (tileCull(r0, r1, tX0, tX1, tY0, tY1))
        atomicAdd(&lc[tx * kNB + q], 1u);
    }
  }
  __syncthreads();

  // ---- intra-block inclusive scan (Hillis-Steele) -> exclusive offsets ----
  unsigned own = lc[t];
  for (int d = 1; d < 256; d <<= 1) {
    unsigned w = (t >= d) ? lc[t - d] : 0u;
    __syncthreads();
    lc[t] += w;
    __syncthreads();
  }
  unsigned excl = lc[t] - own;
  unsigned tot = lc[255];
  if (t == 0) segBase = atomicAdd(&zr[4], tot);
  __syncthreads();
  unsigned sb = segBase;

  unsigned blk = ((unsigned)(b * 32 + ty) * kChunks + (unsigned)c);
  cnt[blk * 257 + t] = sb + excl;
  if (t == 0) cnt[blk * 257 + 256] = sb + tot;
  __syncthreads();
  lc[t] = sb + excl;   // absolute fill cursors
  __syncthreads();

  // ---- pass 2: identical cull -> fill ----
  for (int f = f0 + t; f < f1; f += 256) {
    unsigned pk = tb[bOff + f];
    int cx0 = pk & 0xFF, cx1 = (pk >> 8) & 0xFF;
    int ry0 = (pk >> 16) & 0xFF, ry1 = (pk >> 24) & 0xFF;
    if (ty < ry0 || ty > ry1 || cx0 > cx1) continue;
    const float4* rp = fdP + (bOff + f) * 3;
    float4 r0 = rp[0], r1 = rp[1], r2 = rp[2];
    int q = bucketOf(r2.w, zlo, iscale);
    for (int tx = cx0; tx <= cx1; ++tx) {
      float tX0 = 16.f * tx + 0.5f, tX1 = tX0 + 15.f;
      if (tileCull(r0, r1, tX0, tX1, tY0, tY1)) {
        unsigned pos = atomicAdd(&lc[tx * kNB + q], 1u);
        if (pos < kListCap) list[pos] = (unsigned short)f;
      }
    }
  }
}

// 16x16-pixel tile per 256-thread block -- measured-best R5/R10 structure.
// Per z-bucket (front-to-back): conservative early-break via
// __syncthreads_and; per 256-candidate chunk: barrier, LDS stage, barrier,
// compute. Buckets now span kChunks=8 private subranges; the 72 offsets are
// staged to LDS once and chunks stage from the CONCATENATION of the 8
// ranges (unrolled static-index prefix search -- no scratch spill).
__global__ __launch_bounds__(256) void raster_k(
    const float4* __restrict__ fdP, const float4* __restrict__ fdE,
    const unsigned* __restrict__ cnt, const unsigned short* __restrict__ list,
    const unsigned* __restrict__ zr, const float* __restrict__ verts,
    const float* __restrict__ nacc, const int* __restrict__ faces,
    float* __restrict__ out) {
  __shared__ float4 sA[256], sB[256], sC[256];   // 12 KiB stage
  __shared__ unsigned sOff[kChunks * 9];         // 8 chunks x (8 buckets + end)
  int b = blockIdx.z;
  size_t bOff = (size_t)b * kNF;
  int t = threadIdx.x;
  int tx = t & 15, ty = t >> 4;
  int x = blockIdx.x * 16 + tx;
  int y = blockIdx.y * 16 + ty;
  float xp = (float)x + 0.5f;
  float yp = (float)y + 0.5f;
  bool live = (x < kW && y < kH);
  float zmin = live ? INFINITY : -INFINITY;   // dead px never block the break
  int best = 0x7FFFFFFF;
  float bw0 = 0.f, bw1 = 0.f, bw2 = 0.f;

  float zlo = __uint_as_float(zr[b]);
  float zhi = __uint_as_float(zr[2 + b]);
  float range = zhi - zlo;
  float bwid = range > 1e-30f ? range * (1.f / kNB) : 0.f;

  if (t < kChunks * 9) {
    int c = t / 9, j = t - c * 9;
    unsigned blk = ((unsigned)(b * 32 + blockIdx.y) * kChunks + (unsigned)c);
    sOff[t] = cnt[blk * 257 + blockIdx.x * 8 + j];
  }
  __syncthreads();

  for (int q = 0; q < kNB; ++q) {
    if (q > 0) {
      float lb = zlo + (float)q * bwid * (1.f - 1e-5f) - 2e-5f;
      if (__syncthreads_and(zmin < lb)) break;
    }
    // Concatenated subranges for this bucket (registers, static indices).
    unsigned st[kChunks], pre[kChunks + 1];
    pre[0] = 0;
#pragma unroll
    for (int c = 0; c < kChunks; ++c) {
      unsigned s0 = sOff[c * 9 + q], e0 = sOff[c * 9 + q + 1];
      st[c] = s0;
      pre[c + 1] = pre[c] + (e0 - s0);
    }
    unsigned m = pre[kChunks];
    for (unsigned base = 0; base < m; base += 256) {
      int n = min(256u, m - base);
      __syncthreads();
      if (t < n) {
        unsigned idx = base + t, src = 0;
#pragma unroll
        for (int c = 0; c < kChunks; ++c)
          if (idx >= pre[c] && idx < pre[c + 1]) src = st[c] + (idx - pre[c]);
        unsigned fi = list[src];
        const float4* rp = fdP + (bOff + fi) * 3;
        float4 r0 = rp[0], r1 = rp[1], r2 = rp[2];
        r2.w = __int_as_float((int)fi);
        sA[t] = r0;
        sB[t] = r1;
        sC[t] = r2;
      }
      __syncthreads();
      for (int k = 0; k < n; ++k) {
        float4 a = sA[k], bq = sB[k], c = sC[k];
        float w0a = fmaf(a.x, xp, fmaf(a.y, yp, a.z));
        float w1a = fmaf(bq.x, xp, fmaf(bq.y, yp, bq.z));
        float w2a = 1.f - w0a - w1a;
        float zl = fmaf(c.x, xp, fmaf(c.y, yp, c.z));
        float wmin = fminf(fminf(w0a, w1a), w2a);
        if (wmin >= -a.w && zl <= zmin + bq.w) {
          // Exact path: replicate reference fp32 rounding bit-for-bit.
          int fi = __float_as_int(c.w);
          const float4* ep = fdE + (bOff + fi) * 3;
          float4 e0 = ep[0], e1 = ep[1], e2 = ep[2];
          float dx = __fsub_rn(xp, e0.x), dy = __fsub_rn(yp, e0.y);
          float num0 = __fadd_rn(__fmul_rn(e0.z, dx), __fmul_rn(e0.w, dy));
          float num1 = __fadd_rn(__fmul_rn(e1.x, dx), __fmul_rn(e1.y, dy));
          float w0 = __fdiv_rn(num0, e1.z);
          float w1 = __fdiv_rn(num1, e1.z);
          float w2 = __fsub_rn(__fsub_rn(1.f, w0), w1);
          if (w0 >= 0.f && w1 >= 0.f && w2 >= 0.f) {
            float z = __fadd_rn(
                __fadd_rn(__fmul_rn(w0, e1.w), __fmul_rn(w1, e2.x)),
                __fmul_rn(w2, e2.y));
            if (z < zmin || (z == zmin && fi < best)) {
              zmin = z; best = fi; bw0 = w0; bw1 = w1; bw2 = w2;
            }
          }
        }
      }
    }
  }

  if (!live) return;

  float rv, av;
  if (zmin < INFINITY) {
    int i0 = faces[3 * best + 0], i1 = faces[3 * best + 1], i2 = faces[3 * best + 2];
    const float* vb = verts + (size_t)b * kNV * 3;
    const float* nb = nacc + (size_t)b * kNV * 3;
    float n0x = nb[3 * i0], n0y = nb[3 * i0 + 1], n0z = nb[3 * i0 + 2];
    float n1x = nb[3 * i1], n1y = nb[3 * i1 + 1], n1z = nb[3 * i1 + 2];
    float n2x = nb[3 * i2], n2y = nb[3 * i2 + 1], n2z = nb[3 * i2 + 2];
    float d0 = fmaxf(sqrtf(n0x * n0x + n0y * n0y + n0z * n0z), kEps);
    float d1 = fmaxf(sqrtf(n1x * n1x + n1y * n1y + n1z * n1z), kEps);
    float d2 = fmaxf(sqrtf(n2x * n2x + n2y * n2y + n2z * n2z), kEps);
    n0x /= d0; n0y /= d0; n0z /= d0;
    n1x /= d1; n1y /= d1; n1z /= d1;
    n2x /= d2; n2y /= d2; n2z /= d2;
    float px_ = bw0 * vb[3 * i0 + 0] + bw1 * vb[3 * i1 + 0] + bw2 * vb[3 * i2 + 0];
    float py_ = bw0 * vb[3 * i0 + 1] + bw1 * vb[3 * i1 + 1] + bw2 * vb[3 * i2 + 1];
    float pz_ = bw0 * vb[3 * i0 + 2] + bw1 * vb[3 * i1 + 2] + bw2 * vb[3 * i2 + 2];
    float nx = bw0 * n0x + bw1 * n1x + bw2 * n2x;
    float ny = bw0 * n0y + bw1 * n1y + bw2 * n2y;
    float nz = bw0 * n0z + bw1 * n1z + bw2 * n2z;
    float nn = sqrtf(nx * nx + ny * ny + nz * nz);
    float nd = fmaxf(nn, kEps);
    nx /= nd; ny /= nd; nz /= nd;
    float pn = sqrtf(px_ * px_ + py_ * py_ + pz_ * pz_);
    float pd = fmaxf(pn, kEps);
    float lx = -px_ / pd, ly = -py_ / pd, lz = -pz_ / pd;
    float sdot = nx * lx + ny * ly + nz * lz;
    float ndl = fmaxf(sdot, 0.0f);
    float rx = 2.0f * sdot * nx - lx;
    float ry = 2.0f * sdot * ny - ly;
    float rz = 2.0f * sdot * nz - lz;
    float vdr = fmaxf(lx * rx + ly * ry + lz * rz, 0.0f);
    float qv = vdr;   // vdr^64 via 6 squarings
    qv = qv * qv; qv = qv * qv; qv = qv * qv;
    qv = qv * qv; qv = qv * qv; qv = qv * qv;
    float shade = 0.5f * (0.5f + 0.3f * ndl) + 0.2f * qv;
    rv = fminf(fmaxf(shade, 0.0f), 255.0f);
    av = 1.0f;
  } else {
    rv = 1.0f;
    av = 0.0f;
  }
  ((float4*)out)[((size_t)b * kH + y) * kW + x] = make_float4(rv, rv, rv, av);
}

}  // namespace

extern "C" void kernel_launch(void* const* d_in, const int* in_sizes, int n_in,
                              void* d_out, int out_size, void* d_ws, size_t ws_size,
                              hipStream_t stream) {
  (void)in_sizes; (void)n_in; (void)out_size; (void)ws_size;
  const float* verts = (const float*)d_in[0];   // (B, NV, 3) f32
  const int* faces = (const int*)d_in[1];       // (NF, 3) i32
  float* out = (float*)d_out;                   // (B, H, W, 4) f32
  float* ws = (float*)d_ws;

  // ws layout (float offsets; total ~6.41 MB <= proven ws >= 6.52 MB):
  //   nacc @ 0          (30,138)
  //   fdE  @ 71,680     (float4 x 59,856)
  //   fdP  @ 311,296    (float4 x 59,856)
  //   tb   @ 550,912    (u32 x 19,952)
  //   zr   @ 570,880    (u32 x 8: [0..1]=min(0xFF) [2..3]=max(0) [4]=cursor(0))
  //   cnt  @ 571,008    (u32 x 512*257 = 131,584)
  //   list @ 702,720    (u16 x 1,800,000)
  float* nacc = ws;
  float4* fdE = (float4*)(ws + 71680);
  float4* fdP = (float4*)(ws + 311296);
  unsigned* tb = (unsigned*)(ws + 550912);
  unsigned* zr = (unsigned*)(ws + 570880);
  unsigned* cnt = (unsigned*)(ws + 571008);
  unsigned short* list = (unsigned short*)(ws + 702720);

  hipMemsetAsync(nacc, 0, (size_t)kB * kNV * 3 * sizeof(float), stream);
  hipMemsetAsync(zr, 0xFF, 2 * sizeof(unsigned), stream);       // zrMin
  hipMemsetAsync(zr + 2, 0x00, 3 * sizeof(unsigned), stream);   // zrMax+cursor

  hipLaunchKernelGGL(setup_k, dim3((kNF + 255) / 256, kB), dim3(256), 0,
                     stream, verts, faces, nacc, fdE, fdP, tb, zr);
  hipLaunchKernelGGL(bin_k, dim3(kChunks, 32, kB), dim3(256), 0,
                     stream, fdP, tb, zr, cnt, list);
  hipLaunchKernelGGL(raster_k, dim3(32, 32, kB), dim3(256), 0, stream,
                     fdP, fdE, cnt, list, zr, verts, nacc, faces, out);
}